// Round 7
// baseline (1005.403 us; speedup 1.0000x reference)
//
#include <hip/hip_runtime.h>
#include <stdint.h>

// Problem constants (fixed by reference)
#define BATCH 4
#define LTOT  1408      // NVARS*NPATCH = 22*64
#define HEADS 8
#define HD    64
#define DIMD  512
#define NKEEP 704      // L - int(0.5*L)
#define RBLK  176      // LTOT/8
#define SCAP  32       // sparse-correction capacity per row (max actual = 28)

typedef unsigned int uint;
typedef unsigned short ushort;
typedef __attribute__((ext_vector_type(8))) short bf16x8;
typedef __attribute__((ext_vector_type(4))) float f32x4;

__device__ __forceinline__ uint fkey(float f) {
  // order-preserving map float -> uint (ascending)
  uint u = __float_as_uint(f);
  return u ^ ((uint)((int)u >> 31) | 0x80000000u);
}

// Split f32 into bf16 hi + bf16 lo (x ~= hi + lo, rel err ~2^-17). RNE.
__device__ __forceinline__ void bf16split(float x, ushort& hi, ushort& lo) {
  uint u = __float_as_uint(x);
  uint h = (u + 0x7FFFu + ((u >> 16) & 1u)) & 0xFFFF0000u;
  hi = (ushort)(h >> 16);
  float r = x - __uint_as_float(h);
  uint v = __float_as_uint(r);
  lo = (ushort)((v + 0x7FFFu + ((v >> 16) & 1u)) >> 16);
}

// ---------------------------------------------------------------------------
// GEMM: C[M,N] = A[M,512] * W[N,512]^T.  128x128 tile, BK=16, 256 thr, 8x8 micro.
// MODE 0: qkv — Q,K as bf16 hi/lo planes [B,H,L,64] (q pre-scaled);
//               V as bf16 hi/lo planes TRANSPOSED [B,H,64,L] (for PV B-frags).
// MODE 1: proj — plain f32 store + bias add.
// ---------------------------------------------------------------------------
template<int MODE>
__global__ __launch_bounds__(256)
void gemm_k(const float* __restrict__ A, const float* __restrict__ W,
            const float* __restrict__ pb, ushort* __restrict__ QH,
            ushort* __restrict__ QL, ushort* __restrict__ KH,
            ushort* __restrict__ KL, ushort* __restrict__ VH,
            ushort* __restrict__ VL, float* __restrict__ C0, int ntiles)
{
  __shared__ float Ast[16][132];   // k-major, pad 132 (16B-aligned rows, bank-shifted)
  __shared__ float Bst[16][132];
  const int t  = threadIdx.x;
  const int mt = blockIdx.x / ntiles, nt = blockIdx.x % ntiles;
  const int m0 = mt * 128, n0 = nt * 128;
  const int lr = t >> 2;            // 0..63
  const int lk = (t & 3) << 2;      // 0,4,8,12
  const int tr = t >> 4, tc = t & 15;

  float acc[8][8];
#pragma unroll
  for (int i = 0; i < 8; ++i)
#pragma unroll
    for (int j = 0; j < 8; ++j) acc[i][j] = 0.f;

  for (int k0 = 0; k0 < DIMD; k0 += 16) {
#pragma unroll
    for (int hh = 0; hh < 2; ++hh) {
      const int row = lr + hh * 64;
      const float4 av = *(const float4*)(A + (size_t)(m0 + row) * DIMD + k0 + lk);
      Ast[lk + 0][row] = av.x; Ast[lk + 1][row] = av.y;
      Ast[lk + 2][row] = av.z; Ast[lk + 3][row] = av.w;
      const float4 wv = *(const float4*)(W + (size_t)(n0 + row) * DIMD + k0 + lk);
      Bst[lk + 0][row] = wv.x; Bst[lk + 1][row] = wv.y;
      Bst[lk + 2][row] = wv.z; Bst[lk + 3][row] = wv.w;
    }
    __syncthreads();
#pragma unroll
    for (int k = 0; k < 16; ++k) {
      const float4 a0 = *(const float4*)&Ast[k][tr * 8];
      const float4 a1 = *(const float4*)&Ast[k][tr * 8 + 4];
      const float4 b0 = *(const float4*)&Bst[k][tc * 8];
      const float4 b1 = *(const float4*)&Bst[k][tc * 8 + 4];
      const float a[8] = {a0.x,a0.y,a0.z,a0.w,a1.x,a1.y,a1.z,a1.w};
      const float b[8] = {b0.x,b0.y,b0.z,b0.w,b1.x,b1.y,b1.z,b1.w};
#pragma unroll
      for (int i = 0; i < 8; ++i)
#pragma unroll
        for (int j = 0; j < 8; ++j)
          acc[i][j] = fmaf(a[i], b[j], acc[i][j]);
    }
    __syncthreads();
  }

  const int nb = n0 + tc * 8;
  if (MODE == 0) {
    // n in [0,1536): which = n>>9 (uniform per block), h = (n>>6)&7, d = n&63
    const int which = nb >> 9;
    const int h  = (nb >> 6) & 7;
    const int d0 = nb & 63;
    const float scl = (which == 0) ? 0.125f : 1.0f;   // fold q * HD^-0.5
    if (which == 2) {
      // V transposed: Vt[b,h,d,m], 8 consecutive m per store.
      const int bb = (m0 + tr * 8) / LTOT, ll0 = (m0 + tr * 8) % LTOT;
#pragma unroll
      for (int jp = 0; jp < 8; ++jp) {
        uint hw[4], lw[4];
#pragma unroll
        for (int ip = 0; ip < 4; ++ip) {
          ushort h0, l0v, h1, l1v;
          bf16split(acc[2*ip][jp],     h0, l0v);
          bf16split(acc[2*ip + 1][jp], h1, l1v);
          hw[ip] = (uint)h0 | ((uint)h1 << 16);
          lw[ip] = (uint)l0v | ((uint)l1v << 16);
        }
        const size_t off = ((size_t)(bb * HEADS + h) * 64 + (d0 + jp)) * LTOT + ll0;
        *(uint4*)(VH + off) = make_uint4(hw[0], hw[1], hw[2], hw[3]);
        *(uint4*)(VL + off) = make_uint4(lw[0], lw[1], lw[2], lw[3]);
      }
    } else {
      ushort* Hd = (which == 0) ? QH : KH;
      ushort* Ld = (which == 0) ? QL : KL;
#pragma unroll
      for (int i = 0; i < 8; ++i) {
        const int gm = m0 + tr * 8 + i;
        const int bb = gm / LTOT, ll = gm % LTOT;
        const size_t off = ((size_t)(bb * HEADS + h) * LTOT + ll) * HD + d0;
        uint hw[4], lw[4];
#pragma unroll
        for (int jp = 0; jp < 4; ++jp) {
          ushort h0, l0v, h1, l1v;
          bf16split(acc[i][2*jp]     * scl, h0, l0v);
          bf16split(acc[i][2*jp + 1] * scl, h1, l1v);
          hw[jp] = (uint)h0 | ((uint)h1 << 16);
          lw[jp] = (uint)l0v | ((uint)l1v << 16);
        }
        *(uint4*)(Hd + off) = make_uint4(hw[0], hw[1], hw[2], hw[3]);
        *(uint4*)(Ld + off) = make_uint4(lw[0], lw[1], lw[2], lw[3]);
      }
    }
  } else {
    const float4 q0 = *(const float4*)(pb + nb);
    const float4 q1 = *(const float4*)(pb + nb + 4);
#pragma unroll
    for (int i = 0; i < 8; ++i) {
      const int gm = m0 + tr * 8 + i;
      float* p = C0 + (size_t)gm * DIMD + nb;
      float4 v0 = make_float4(acc[i][0]+q0.x, acc[i][1]+q0.y, acc[i][2]+q0.z, acc[i][3]+q0.w);
      float4 v1 = make_float4(acc[i][4]+q1.x, acc[i][5]+q1.y, acc[i][6]+q1.z, acc[i][7]+q1.w);
      *(float4*)p = v0;
      *(float4*)(p + 4) = v1;
    }
  }
}

// ---------------------------------------------------------------------------
// Sparse-bias builder. bias[h,l,m] = w2[h] (row-const, ordering/softmax
// invariant -> skipped) + (w0-w2)*S[l,m] + (w1-w2)*T[l,m] - w2*eye[l,m].
// <=28 sparse entries/row. One wave per row l, ballot compaction.
// ---------------------------------------------------------------------------
__global__ __launch_bounds__(256)
void sbias_k(const float* __restrict__ masks, int* __restrict__ sIdx,
             float* __restrict__ sCoef, int* __restrict__ sCnt)
{
  const int l    = blockIdx.x * 4 + (threadIdx.x >> 6);   // 352 blocks * 4 waves
  const int lane = threadIdx.x & 63;
  const unsigned long long ltmask = (1ull << lane) - 1ull;
  const float* Sm = masks + ((size_t)l * 3 + 0) * LTOT;
  const float* Tm = masks + ((size_t)l * 3 + 1) * LTOT;
  int base = 0;
  for (int i = lane; i < LTOT; i += 64) {
    const float sv = Sm[i];
    const float tv = Tm[i];
    const unsigned long long bS = __ballot(sv != 0.f);
    if (sv != 0.f) {
      const int pos = base + __popcll(bS & ltmask);
      if (pos < SCAP) { sIdx[l * SCAP + pos] = (i << 2) | 0; sCoef[l * SCAP + pos] = sv; }
    }
    base += __popcll(bS);
    const unsigned long long bT = __ballot(tv != 0.f);
    if (tv != 0.f) {
      const int pos = base + __popcll(bT & ltmask);
      if (pos < SCAP) { sIdx[l * SCAP + pos] = (i << 2) | 1; sCoef[l * SCAP + pos] = tv; }
    }
    base += __popcll(bT);
    const unsigned long long bD = __ballot(i == l);
    if (i == l) {
      const int pos = base + __popcll(bD & ltmask);
      if (pos < SCAP) { sIdx[l * SCAP + pos] = (i << 2) | 2; sCoef[l * SCAP + pos] = 1.f; }
    }
    base += __popcll(bD);
  }
  if (lane == 0) sCnt[l] = (base < SCAP) ? base : SCAP;
}

// ---------------------------------------------------------------------------
// Fused attention: per block = 8 query rows of one (b,h).
// Scores: bf16 MFMA 16x16x32, 3-term hi/lo; K B-frags straight from L2; D
//   written into row-major S2[8][1408] f32 (scan-phase conflict-free).
// Then: sparse bias -> exact top-704 radix select (stride-1 scans) ->
//   softmax packs P as (bf16hi|bf16lo) uint IN PLACE, col-XOR (r&3)<<3
//   (bits 3-4 only: write-set == read-set per lockstep iteration -> race-free;
//   bit 5 would cross the stride-32 iteration boundary AND adds no bank
//   spread, since bank = word mod 32) ->
//   PV on MFMA: A-frags unpacked from S2, B-frags = transposed V hi/lo planes
//   from L2; 3-term hi/lo; cross-wave reduce in red, /Z, store.
// LDS: S2 44KB + U 8.3KB (hist 16x129 | red 2048f | rowZ) = 53.4KB => 3 blk/CU.
// Grid XCD-chunk swizzled: one (b,h)'s row-blocks share an XCD's L2.
// ---------------------------------------------------------------------------
__global__ __launch_bounds__(256, 3)
void attn_k(const ushort* __restrict__ QH, const ushort* __restrict__ QL,
            const ushort* __restrict__ KH, const ushort* __restrict__ KL,
            const ushort* __restrict__ VH, const ushort* __restrict__ VL,
            const float* __restrict__ rw,
            const int* __restrict__ sIdx, const float* __restrict__ sCoef,
            const int* __restrict__ sCnt, float* __restrict__ AO)
{
  __shared__ float S2[8 * LTOT];       // 45056B row-major: S2[r*1408 + m]
  __shared__ uint  U[2080];            // 8320B: hist 16*129 | red 2048 f32; rowZ @2072

  const int t   = threadIdx.x;
  // XCD-chunked bijective swizzle: 5632 = 8 * 704 exactly.
  const int bid = (int)((blockIdx.x & 7) * 704 + (blockIdx.x >> 3));
  const int bh = bid / RBLK;
  const int rb = bid % RBLK;
  const int l0 = rb * 8;
  const int b  = bh >> 3, h = bh & 7;

  const int lane = t & 63;
  const int g    = t >> 6;             // wave id

  // ---------------- scores (MFMA, no barriers) ----------------
  {
    // A-frags: row = lane&15 (rows 8-15 junk, discarded), k = 8*(lane>>4)+j.
    int ar = l0 + (lane & 15);
    if (ar >= LTOT) ar = LTOT - 1;
    const size_t qb = ((size_t)bh * LTOT + ar) * HD + 8 * (lane >> 4);
    const bf16x8 aH0 = *(const bf16x8*)(QH + qb);
    const bf16x8 aH1 = *(const bf16x8*)(QH + qb + 32);
    const bf16x8 aL0 = *(const bf16x8*)(QL + qb);
    const bf16x8 aL1 = *(const bf16x8*)(QL + qb + 32);

#pragma unroll 2
    for (int it = 0; it < 22; ++it) {
      const int m = g * 352 + it * 16 + (lane & 15);   // B col = lane&15
      const size_t kb = ((size_t)bh * LTOT + m) * HD + 8 * (lane >> 4);
      const bf16x8 bH0 = *(const bf16x8*)(KH + kb);
      const bf16x8 bH1 = *(const bf16x8*)(KH + kb + 32);
      const bf16x8 bL0 = *(const bf16x8*)(KL + kb);
      const bf16x8 bL1 = *(const bf16x8*)(KL + kb + 32);
      f32x4 acc = {0.f, 0.f, 0.f, 0.f};
      acc = __builtin_amdgcn_mfma_f32_16x16x32_bf16(aH0, bH0, acc, 0, 0, 0);
      acc = __builtin_amdgcn_mfma_f32_16x16x32_bf16(aH1, bH1, acc, 0, 0, 0);
      acc = __builtin_amdgcn_mfma_f32_16x16x32_bf16(aH0, bL0, acc, 0, 0, 0);
      acc = __builtin_amdgcn_mfma_f32_16x16x32_bf16(aH1, bL1, acc, 0, 0, 0);
      acc = __builtin_amdgcn_mfma_f32_16x16x32_bf16(aL0, bH0, acc, 0, 0, 0);
      acc = __builtin_amdgcn_mfma_f32_16x16x32_bf16(aL1, bH1, acc, 0, 0, 0);
      // D: col=lane&15 (=m), row=4*(lane>>4)+reg; rows 0-7 live in lanes 0-31.
      if (lane < 32) {
        const int r0 = 4 * (lane >> 4);
        S2[(r0 + 0) * LTOT + m] = acc[0];
        S2[(r0 + 1) * LTOT + m] = acc[1];
        S2[(r0 + 2) * LTOT + m] = acc[2];
        S2[(r0 + 3) * LTOT + m] = acc[3];
      }
    }
  }
  __syncthreads();

  // ---------------- sparse bias corrections (<=28 per row) ----------------
  {
    const int rr = t >> 5, jj = t & 31;
    const int l  = l0 + rr;
    if (jj < sCnt[l]) {
      const int   e = sIdx[l * SCAP + jj];
      const float c = sCoef[l * SCAP + jj];
      const int   m = e >> 2, ty = e & 3;
      const float w0 = rw[h * 3 + 0], w1 = rw[h * 3 + 1], w2 = rw[h * 3 + 2];
      const float d = (ty == 0) ? (w0 - w2) * c
                    : (ty == 1) ? (w1 - w2) * c
                                : -w2 * c;
      S2[rr * LTOT + m] += d;     // unique (m,rr) per entry -> no atomics
    }
  }
  // (radix pass 0 begins with __syncthreads)

  // ---------------- exact top-NKEEP threshold (radix select) ----------------
  const int r = t >> 5, j = t & 31;     // 32 threads per row
  uint* hist = U;                        // 16 sub-hists (2/row) of 129 u16-pair words
  uint prefix = 0, rem = NKEEP;
  for (int p = 0; p < 4; ++p) {
    const int shift = 24 - 8 * p;
    const uint himask = (p == 0) ? 0u : (0xFFFFFFFFu << (8 * (4 - p)));
    __syncthreads();
    for (int i = t; i < 16 * 129; i += 256) hist[i] = 0;
    __syncthreads();
    uint* hr = hist + (r * 2 + (j & 1)) * 129;
    for (int i = j; i < LTOT; i += 32) {        // stride-1 per team: conflict-free
      const uint u = fkey(S2[r * LTOT + i]);
      if ((u & himask) == prefix) {
        const uint bin = (u >> shift) & 255u;
        atomicAdd(&hr[bin >> 1], (bin & 1) ? 65536u : 1u);
      }
    }
    __syncthreads();
    // lane j covers bins [8j, 8j+7]
    uint c = 0;
#pragma unroll
    for (int bb = 0; bb < 8; ++bb) {
      const int bin = j * 8 + bb;
      const uint w = hist[(r*2+0)*129 + (bin>>1)] + hist[(r*2+1)*129 + (bin>>1)];
      c += (bin & 1) ? (w >> 16) : (w & 0xFFFFu);
    }
    uint sfx = c;  // suffix sum over lanes >= j (descending-bin cumulative)
#pragma unroll
    for (int off = 1; off < 32; off <<= 1) {
      const uint o = __shfl_down(sfx, off, 32);
      if (j + off < 32) sfx += o;
    }
    const unsigned long long bal = __ballot(sfx >= rem);
    const uint halfb = (uint)(bal >> (t & 32));
    const int gs = 31 - __clz((int)halfb);         // highest lane with sfx >= rem
    uint above = __shfl(sfx, (gs + 1) & 31, 32);
    if (gs == 31) above = 0;
    uint rem2 = rem - above;
    int selbin = gs * 8;
#pragma unroll
    for (int bb = 7; bb >= 0; --bb) {
      const int bin = gs * 8 + bb;
      const uint w = hist[(r*2+0)*129 + (bin>>1)] + hist[(r*2+1)*129 + (bin>>1)];
      const uint cnt = (bin & 1) ? (w >> 16) : (w & 0xFFFFu);
      if (rem2 <= cnt) { selbin = bin; break; }
      rem2 -= cnt;
    }
    prefix |= ((uint)selbin) << shift;
    rem = rem2;
  }
  const uint T = prefix;   // key of the NKEEP-th largest score in this row

  // ---------------- softmax over kept; pack P=(bf16hi|bf16lo) in place ------
  float mx = -3.0e38f;
  for (int i = j; i < LTOT; i += 32) mx = fmaxf(mx, S2[r * LTOT + i]);
#pragma unroll
  for (int off = 16; off; off >>= 1) mx = fmaxf(mx, __shfl_xor(mx, off, 32));
  float z = 0.f;
  {
    const int xr = (r & 3) << 3;        // bits 3-4 only: race-free, full bank spread
    uint* S2u = (uint*)S2;
    for (int i = j; i < LTOT; i += 32) {
      const float s = S2[r * LTOT + i];
      const float e = (fkey(s) >= T) ? __expf(s - mx) : 0.f;
      z += e;
      ushort ph, pl; bf16split(e, ph, pl);
      S2u[r * LTOT + (i ^ xr)] = (uint)ph | ((uint)pl << 16);
    }
  }
#pragma unroll
  for (int off = 16; off; off >>= 1) z += __shfl_xor(z, off, 32);
  float* rowZ = (float*)&U[2072];
  if (j == 0) rowZ[r] = z;
  __syncthreads();

  // ---------------- PV: MFMA, split-m across waves ----------------
  {
    f32x4 acc[4];
#pragma unroll
    for (int nt = 0; nt < 4; ++nt) acc[nt] = f32x4{0.f, 0.f, 0.f, 0.f};
    const int h4 = lane >> 4;
    const int arow = ((lane & 15) < 8) ? (lane & 15) : 7;   // clamp junk rows
    const int xr = (arow & 3) << 3;                          // matches pack swizzle
    const uint* S2u = (const uint*)S2;
    const size_t vbase = (size_t)bh * 64 * LTOT;
    for (int ks = 0; ks < 11; ++ks) {
      const int mw = g * 352 + ks * 32 + 8 * h4;
      const int W0 = arow * LTOT + (mw ^ xr);
      const uint4 ua = *(const uint4*)&S2u[W0];
      const uint4 ub = *(const uint4*)&S2u[W0 + 4];
      uint4 ahv, alv;
      ahv.x = (ua.x & 0xFFFFu) | (ua.y << 16);
      alv.x = (ua.x >> 16) | (ua.y & 0xFFFF0000u);
      ahv.y = (ua.z & 0xFFFFu) | (ua.w << 16);
      alv.y = (ua.z >> 16) | (ua.w & 0xFFFF0000u);
      ahv.z = (ub.x & 0xFFFFu) | (ub.y << 16);
      alv.z = (ub.x >> 16) | (ub.y & 0xFFFF0000u);
      ahv.w = (ub.z & 0xFFFFu) | (ub.w << 16);
      alv.w = (ub.z >> 16) | (ub.w & 0xFFFF0000u);
      const bf16x8 aH = *(const bf16x8*)&ahv;
      const bf16x8 aL = *(const bf16x8*)&alv;
#pragma unroll
      for (int nt = 0; nt < 4; ++nt) {
        const size_t vo = vbase + (size_t)(nt * 16 + (lane & 15)) * LTOT + mw;
        const bf16x8 bH = *(const bf16x8*)(VH + vo);
        const bf16x8 bL = *(const bf16x8*)(VL + vo);
        acc[nt] = __builtin_amdgcn_mfma_f32_16x16x32_bf16(aH, bH, acc[nt], 0, 0, 0);
        acc[nt] = __builtin_amdgcn_mfma_f32_16x16x32_bf16(aH, bL, acc[nt], 0, 0, 0);
        acc[nt] = __builtin_amdgcn_mfma_f32_16x16x32_bf16(aL, bH, acc[nt], 0, 0, 0);
      }
    }
    float* red = (float*)U;   // [4][8][64]
    if (lane < 32) {
#pragma unroll
      for (int nt = 0; nt < 4; ++nt)
#pragma unroll
        for (int q = 0; q < 4; ++q)
          red[g * 512 + (4 * h4 + q) * 64 + nt * 16 + (lane & 15)] = acc[nt][q];
    }
  }
  __syncthreads();
  {
    float* red = (float*)U;
    float* rowZp = (float*)&U[2072];
    for (int idx = t; idx < 512; idx += 256) {
      const int rr = idx >> 6, ln = idx & 63;
      const float o = (red[rr*64+ln] + red[512 + rr*64+ln] +
                       red[1024 + rr*64+ln] + red[1536 + rr*64+ln]) / rowZp[rr];
      AO[((size_t)b * LTOT + (l0 + rr)) * DIMD + h * HD + ln] = o;
    }
  }
}

// ---------------------------------------------------------------------------
extern "C" void kernel_launch(void* const* d_in, const int* in_sizes, int n_in,
                              void* d_out, int out_size, void* d_ws, size_t ws_size,
                              hipStream_t stream)
{
  (void)in_sizes; (void)n_in; (void)out_size; (void)ws_size;
  const float* x  = (const float*)d_in[0];
  const float* qw = (const float*)d_in[1];
  const float* pw = (const float*)d_in[2];
  const float* pb = (const float*)d_in[3];
  const float* rw = (const float*)d_in[4];
  const float* rm = (const float*)d_in[5];
  float* out = (float*)d_out;
  float* ws  = (float*)d_ws;

  const size_t NQ = (size_t)BATCH * HEADS * LTOT * HD;     // 2,883,584 elems
  ushort* QH = (ushort*)ws;            // 6 ushort planes = 3*NQ floats
  ushort* QL = QH + NQ;
  ushort* KH = QH + 2 * NQ;
  ushort* KL = QH + 3 * NQ;
  ushort* VH = QH + 4 * NQ;            // transposed [B,H,64,L]
  ushort* VL = QH + 5 * NQ;
  float*  AO = ws + 3 * NQ;                                 // [B, L, 512]
  float*  sCo = ws + 4 * NQ;                                // 1408*32 floats
  int*    sId = (int*)(ws + 4 * NQ + LTOT * SCAP);          // 1408*32 ints
  int*    sCn = (int*)(ws + 4 * NQ + 2 * LTOT * SCAP);      // 1408 ints
  // total ws: 4*NQ + 2*45,056 + 1,408 floats = 46.5 MB

  sbias_k<<<dim3(352), dim3(256), 0, stream>>>(rm, sId, sCo, sCn);
  gemm_k<0><<<dim3(44 * 12), dim3(256), 0, stream>>>(x, qw, nullptr, QH, QL, KH, KL, VH, VL, nullptr, 12);
  attn_k<<<dim3(32 * RBLK), dim3(256), 0, stream>>>(QH, QL, KH, KL, VH, VL, rw, sId, sCo, sCn, AO);
  gemm_k<1><<<dim3(44 * 4), dim3(256), 0, stream>>>(AO, pw, pb, nullptr, nullptr, nullptr, nullptr, nullptr, nullptr, out, 4);
}

// Round 9
// 900.006 us; speedup vs baseline: 1.1171x; 1.1171x over previous
//
#include <hip/hip_runtime.h>
#include <stdint.h>

// Problem constants (fixed by reference)
#define BATCH 4
#define LTOT  1408      // NVARS*NPATCH = 22*64
#define HEADS 8
#define HD    64
#define DIMD  512
#define NKEEP 704      // L - int(0.5*L)
#define RBLK  176      // LTOT/8
#define SCAP  32       // sparse-correction capacity per row (max actual = 28)

typedef unsigned int uint;
typedef unsigned short ushort;
typedef __attribute__((ext_vector_type(8))) short bf16x8;
typedef __attribute__((ext_vector_type(4))) float f32x4;

__device__ __forceinline__ uint fkey(float f) {
  // order-preserving map float -> uint (ascending)
  uint u = __float_as_uint(f);
  return u ^ ((uint)((int)u >> 31) | 0x80000000u);
}

// Split f32 into bf16 hi + bf16 lo (x ~= hi + lo, rel err ~2^-17). RNE.
__device__ __forceinline__ void bf16split(float x, ushort& hi, ushort& lo) {
  uint u = __float_as_uint(x);
  uint h = (u + 0x7FFFu + ((u >> 16) & 1u)) & 0xFFFF0000u;
  hi = (ushort)(h >> 16);
  float r = x - __uint_as_float(h);
  uint v = __float_as_uint(r);
  lo = (ushort)((v + 0x7FFFu + ((v >> 16) & 1u)) >> 16);
}

// ---------------------------------------------------------------------------
// GEMM: C[M,N] = A[M,512] * W[N,512]^T.  128x128 tile, BK=16, 256 thr, 8x8 micro.
// MODE 0: qkv — Q,K as bf16 hi/lo planes [B,H,L,64] (q pre-scaled);
//               V as bf16 hi/lo planes TRANSPOSED [B,H,64,L] (for PV B-frags).
// MODE 1: proj — plain f32 store + bias add.
// ---------------------------------------------------------------------------
template<int MODE>
__global__ __launch_bounds__(256)
void gemm_k(const float* __restrict__ A, const float* __restrict__ W,
            const float* __restrict__ pb, ushort* __restrict__ QH,
            ushort* __restrict__ QL, ushort* __restrict__ KH,
            ushort* __restrict__ KL, ushort* __restrict__ VH,
            ushort* __restrict__ VL, float* __restrict__ C0, int ntiles)
{
  __shared__ float Ast[16][132];   // k-major, pad 132 (16B-aligned rows, bank-shifted)
  __shared__ float Bst[16][132];
  const int t  = threadIdx.x;
  const int mt = blockIdx.x / ntiles, nt = blockIdx.x % ntiles;
  const int m0 = mt * 128, n0 = nt * 128;
  const int lr = t >> 2;            // 0..63
  const int lk = (t & 3) << 2;      // 0,4,8,12
  const int tr = t >> 4, tc = t & 15;

  float acc[8][8];
#pragma unroll
  for (int i = 0; i < 8; ++i)
#pragma unroll
    for (int j = 0; j < 8; ++j) acc[i][j] = 0.f;

  for (int k0 = 0; k0 < DIMD; k0 += 16) {
#pragma unroll
    for (int hh = 0; hh < 2; ++hh) {
      const int row = lr + hh * 64;
      const float4 av = *(const float4*)(A + (size_t)(m0 + row) * DIMD + k0 + lk);
      Ast[lk + 0][row] = av.x; Ast[lk + 1][row] = av.y;
      Ast[lk + 2][row] = av.z; Ast[lk + 3][row] = av.w;
      const float4 wv = *(const float4*)(W + (size_t)(n0 + row) * DIMD + k0 + lk);
      Bst[lk + 0][row] = wv.x; Bst[lk + 1][row] = wv.y;
      Bst[lk + 2][row] = wv.z; Bst[lk + 3][row] = wv.w;
    }
    __syncthreads();
#pragma unroll
    for (int k = 0; k < 16; ++k) {
      const float4 a0 = *(const float4*)&Ast[k][tr * 8];
      const float4 a1 = *(const float4*)&Ast[k][tr * 8 + 4];
      const float4 b0 = *(const float4*)&Bst[k][tc * 8];
      const float4 b1 = *(const float4*)&Bst[k][tc * 8 + 4];
      const float a[8] = {a0.x,a0.y,a0.z,a0.w,a1.x,a1.y,a1.z,a1.w};
      const float b[8] = {b0.x,b0.y,b0.z,b0.w,b1.x,b1.y,b1.z,b1.w};
#pragma unroll
      for (int i = 0; i < 8; ++i)
#pragma unroll
        for (int j = 0; j < 8; ++j)
          acc[i][j] = fmaf(a[i], b[j], acc[i][j]);
    }
    __syncthreads();
  }

  const int nb = n0 + tc * 8;
  if (MODE == 0) {
    // n in [0,1536): which = n>>9 (uniform per block), h = (n>>6)&7, d = n&63
    const int which = nb >> 9;
    const int h  = (nb >> 6) & 7;
    const int d0 = nb & 63;
    const float scl = (which == 0) ? 0.125f : 1.0f;   // fold q * HD^-0.5
    if (which == 2) {
      // V transposed: Vt[b,h,d,m], 8 consecutive m per store.
      const int bb = (m0 + tr * 8) / LTOT, ll0 = (m0 + tr * 8) % LTOT;
#pragma unroll
      for (int jp = 0; jp < 8; ++jp) {
        uint hw[4], lw[4];
#pragma unroll
        for (int ip = 0; ip < 4; ++ip) {
          ushort h0, l0v, h1, l1v;
          bf16split(acc[2*ip][jp],     h0, l0v);
          bf16split(acc[2*ip + 1][jp], h1, l1v);
          hw[ip] = (uint)h0 | ((uint)h1 << 16);
          lw[ip] = (uint)l0v | ((uint)l1v << 16);
        }
        const size_t off = ((size_t)(bb * HEADS + h) * 64 + (d0 + jp)) * LTOT + ll0;
        *(uint4*)(VH + off) = make_uint4(hw[0], hw[1], hw[2], hw[3]);
        *(uint4*)(VL + off) = make_uint4(lw[0], lw[1], lw[2], lw[3]);
      }
    } else {
      ushort* Hd = (which == 0) ? QH : KH;
      ushort* Ld = (which == 0) ? QL : KL;
#pragma unroll
      for (int i = 0; i < 8; ++i) {
        const int gm = m0 + tr * 8 + i;
        const int bb = gm / LTOT, ll = gm % LTOT;
        const size_t off = ((size_t)(bb * HEADS + h) * LTOT + ll) * HD + d0;
        uint hw[4], lw[4];
#pragma unroll
        for (int jp = 0; jp < 4; ++jp) {
          ushort h0, l0v, h1, l1v;
          bf16split(acc[i][2*jp]     * scl, h0, l0v);
          bf16split(acc[i][2*jp + 1] * scl, h1, l1v);
          hw[jp] = (uint)h0 | ((uint)h1 << 16);
          lw[jp] = (uint)l0v | ((uint)l1v << 16);
        }
        *(uint4*)(Hd + off) = make_uint4(hw[0], hw[1], hw[2], hw[3]);
        *(uint4*)(Ld + off) = make_uint4(lw[0], lw[1], lw[2], lw[3]);
      }
    }
  } else {
    const float4 q0 = *(const float4*)(pb + nb);
    const float4 q1 = *(const float4*)(pb + nb + 4);
#pragma unroll
    for (int i = 0; i < 8; ++i) {
      const int gm = m0 + tr * 8 + i;
      float* p = C0 + (size_t)gm * DIMD + nb;
      float4 v0 = make_float4(acc[i][0]+q0.x, acc[i][1]+q0.y, acc[i][2]+q0.z, acc[i][3]+q0.w);
      float4 v1 = make_float4(acc[i][4]+q1.x, acc[i][5]+q1.y, acc[i][6]+q1.z, acc[i][7]+q1.w);
      *(float4*)p = v0;
      *(float4*)(p + 4) = v1;
    }
  }
}

// ---------------------------------------------------------------------------
// Sparse-bias builder. bias[h,l,m] = w2[h] (row-const, ordering/softmax
// invariant -> skipped) + (w0-w2)*S[l,m] + (w1-w2)*T[l,m] - w2*eye[l,m].
// <=28 sparse entries/row. One wave per row l, ballot compaction.
// ---------------------------------------------------------------------------
__global__ __launch_bounds__(256)
void sbias_k(const float* __restrict__ masks, int* __restrict__ sIdx,
             float* __restrict__ sCoef, int* __restrict__ sCnt)
{
  const int l    = blockIdx.x * 4 + (threadIdx.x >> 6);   // 352 blocks * 4 waves
  const int lane = threadIdx.x & 63;
  const unsigned long long ltmask = (1ull << lane) - 1ull;
  const float* Sm = masks + ((size_t)l * 3 + 0) * LTOT;
  const float* Tm = masks + ((size_t)l * 3 + 1) * LTOT;
  int base = 0;
  for (int i = lane; i < LTOT; i += 64) {
    const float sv = Sm[i];
    const float tv = Tm[i];
    const unsigned long long bS = __ballot(sv != 0.f);
    if (sv != 0.f) {
      const int pos = base + __popcll(bS & ltmask);
      if (pos < SCAP) { sIdx[l * SCAP + pos] = (i << 2) | 0; sCoef[l * SCAP + pos] = sv; }
    }
    base += __popcll(bS);
    const unsigned long long bT = __ballot(tv != 0.f);
    if (tv != 0.f) {
      const int pos = base + __popcll(bT & ltmask);
      if (pos < SCAP) { sIdx[l * SCAP + pos] = (i << 2) | 1; sCoef[l * SCAP + pos] = tv; }
    }
    base += __popcll(bT);
    const unsigned long long bD = __ballot(i == l);
    if (i == l) {
      const int pos = base + __popcll(bD & ltmask);
      if (pos < SCAP) { sIdx[l * SCAP + pos] = (i << 2) | 2; sCoef[l * SCAP + pos] = 1.f; }
    }
    base += __popcll(bD);
  }
  if (lane == 0) sCnt[l] = (base < SCAP) ? base : SCAP;
}

// ---------------------------------------------------------------------------
// Fused attention: per block = 8 query rows of one (b,h).
// Scores: bf16 MFMA, 3-term hi/lo, DEPTH-2 SW PIPELINE over 32-col groups
//   (8 K-frag loads in flight while 12 MFMAs run). Row-major S2 f32.
// PV ks=0 V-frags pre-issued BEFORE radix (latency hidden under ~10k cyc of
//   select/softmax; reg loads are not drained by barriers).
// Radix top-704 (stride-1 scans) -> softmax packs P=(bf16hi|lo) in place,
//   col-XOR (r&3)<<3 -> PV MFMA with depth-2 V prefetch -> reduce, /Z, store.
// LDS: S2 44KB + U 8.3KB = 53.4KB => 3 blk/CU. XCD-chunked block swizzle.
// ---------------------------------------------------------------------------
__global__ __launch_bounds__(256, 3)
void attn_k(const ushort* __restrict__ QH, const ushort* __restrict__ QL,
            const ushort* __restrict__ KH, const ushort* __restrict__ KL,
            const ushort* __restrict__ VH, const ushort* __restrict__ VL,
            const float* __restrict__ rw,
            const int* __restrict__ sIdx, const float* __restrict__ sCoef,
            const int* __restrict__ sCnt, float* __restrict__ AO)
{
  __shared__ float S2[8 * LTOT];       // 45056B row-major: S2[r*1408 + m]
  __shared__ uint  U[2080];            // 8320B: hist 16*129 | red 2048 f32; rowZ @2072

  const int t   = threadIdx.x;
  // XCD-chunked bijective swizzle: 5632 = 8 * 704 exactly.
  const int bid = (int)((blockIdx.x & 7) * 704 + (blockIdx.x >> 3));
  const int bh = bid / RBLK;
  const int rb = bid % RBLK;
  const int l0 = rb * 8;
  const int b  = bh >> 3, h = bh & 7;

  const int lane = t & 63;
  const int g    = t >> 6;             // wave id
  const int c15  = lane & 15;
  const int h4   = lane >> 4;

  // ---------------- scores (MFMA, depth-2 software pipeline) ----------------
  {
    int ar = l0 + c15;
    if (ar >= LTOT) ar = LTOT - 1;
    const size_t qb = ((size_t)bh * LTOT + ar) * HD + 8 * h4;
    const bf16x8 aH0 = *(const bf16x8*)(QH + qb);
    const bf16x8 aH1 = *(const bf16x8*)(QH + qb + 32);
    const bf16x8 aL0 = *(const bf16x8*)(QL + qb);
    const bf16x8 aL1 = *(const bf16x8*)(QL + qb + 32);

    const size_t kb0 = (size_t)bh * LTOT * HD + 8 * h4;
    const int mb = g * 352 + c15;

    bf16x8 cA0,cA1,cA2,cA3, cB0,cB1,cB2,cB3;
    bf16x8 nA0,nA1,nA2,nA3, nB0,nB1,nB2,nB3;
#define LDK4(d0,d1,d2,d3, mcol) do { const size_t kk = kb0 + (size_t)(mcol) * HD; \
    d0 = *(const bf16x8*)(KH + kk); d1 = *(const bf16x8*)(KH + kk + 32); \
    d2 = *(const bf16x8*)(KL + kk); d3 = *(const bf16x8*)(KL + kk + 32); } while(0)
    LDK4(cA0,cA1,cA2,cA3, mb);
    LDK4(cB0,cB1,cB2,cB3, mb + 16);
#pragma unroll
    for (int it = 0; it < 11; ++it) {
      if (it < 10) {
        LDK4(nA0,nA1,nA2,nA3, mb + (it + 1) * 32);
        LDK4(nB0,nB1,nB2,nB3, mb + (it + 1) * 32 + 16);
      }
      f32x4 s0 = {0.f,0.f,0.f,0.f}, s1 = {0.f,0.f,0.f,0.f};
      __builtin_amdgcn_s_setprio(1);
      s0 = __builtin_amdgcn_mfma_f32_16x16x32_bf16(aH0, cA0, s0, 0, 0, 0);
      s1 = __builtin_amdgcn_mfma_f32_16x16x32_bf16(aH0, cB0, s1, 0, 0, 0);
      s0 = __builtin_amdgcn_mfma_f32_16x16x32_bf16(aH1, cA1, s0, 0, 0, 0);
      s1 = __builtin_amdgcn_mfma_f32_16x16x32_bf16(aH1, cB1, s1, 0, 0, 0);
      s0 = __builtin_amdgcn_mfma_f32_16x16x32_bf16(aH0, cA2, s0, 0, 0, 0);
      s1 = __builtin_amdgcn_mfma_f32_16x16x32_bf16(aH0, cB2, s1, 0, 0, 0);
      s0 = __builtin_amdgcn_mfma_f32_16x16x32_bf16(aH1, cA3, s0, 0, 0, 0);
      s1 = __builtin_amdgcn_mfma_f32_16x16x32_bf16(aH1, cB3, s1, 0, 0, 0);
      s0 = __builtin_amdgcn_mfma_f32_16x16x32_bf16(aL0, cA0, s0, 0, 0, 0);
      s1 = __builtin_amdgcn_mfma_f32_16x16x32_bf16(aL0, cB0, s1, 0, 0, 0);
      s0 = __builtin_amdgcn_mfma_f32_16x16x32_bf16(aL1, cA1, s0, 0, 0, 0);
      s1 = __builtin_amdgcn_mfma_f32_16x16x32_bf16(aL1, cB1, s1, 0, 0, 0);
      __builtin_amdgcn_s_setprio(0);
      if (lane < 32) {
        const int r0 = 4 * h4;            // h4 in {0,1} here
        const int mA = g * 352 + it * 32 + c15;
        S2[(r0 + 0) * LTOT + mA] = s0[0];
        S2[(r0 + 1) * LTOT + mA] = s0[1];
        S2[(r0 + 2) * LTOT + mA] = s0[2];
        S2[(r0 + 3) * LTOT + mA] = s0[3];
        S2[(r0 + 0) * LTOT + mA + 16] = s1[0];
        S2[(r0 + 1) * LTOT + mA + 16] = s1[1];
        S2[(r0 + 2) * LTOT + mA + 16] = s1[2];
        S2[(r0 + 3) * LTOT + mA + 16] = s1[3];
      }
      cA0 = nA0; cA1 = nA1; cA2 = nA2; cA3 = nA3;
      cB0 = nB0; cB1 = nB1; cB2 = nB2; cB3 = nB3;
    }
#undef LDK4
  }
  __syncthreads();

  // ---- pre-issue PV ks=0 V-frags NOW: latency hides under radix+softmax ----
  const size_t vb0 = (size_t)bh * 64 * LTOT + (size_t)c15 * LTOT + g * 352 + 8 * h4;
#define LDV(dH, dL, ntv, ksv) do { const size_t vv = vb0 + (size_t)(ntv) * 16 * LTOT + (ksv) * 32; \
    dH = *(const bf16x8*)(VH + vv); dL = *(const bf16x8*)(VL + vv); } while(0)
  bf16x8 vc0,vc1,vc2,vc3,vc4,vc5,vc6,vc7;
  LDV(vc0,vc1, 0,0); LDV(vc2,vc3, 1,0); LDV(vc4,vc5, 2,0); LDV(vc6,vc7, 3,0);

  // ---------------- sparse bias corrections (<=28 per row) ----------------
  {
    const int rr = t >> 5, jj = t & 31;
    const int l  = l0 + rr;
    if (jj < sCnt[l]) {
      const int   e = sIdx[l * SCAP + jj];
      const float c = sCoef[l * SCAP + jj];
      const int   m = e >> 2, ty = e & 3;
      const float w0 = rw[h * 3 + 0], w1 = rw[h * 3 + 1], w2 = rw[h * 3 + 2];
      const float d = (ty == 0) ? (w0 - w2) * c
                    : (ty == 1) ? (w1 - w2) * c
                                : -w2 * c;
      S2[rr * LTOT + m] += d;     // unique (m,rr) per entry -> no atomics
    }
  }
  // (radix pass 0 begins with __syncthreads)

  // ---------------- exact top-NKEEP threshold (radix select) ----------------
  const int r = t >> 5, j = t & 31;     // 32 threads per row
  uint* hist = U;                        // 16 sub-hists (2/row) of 129 u16-pair words
  uint prefix = 0, rem = NKEEP;
  for (int p = 0; p < 4; ++p) {
    const int shift = 24 - 8 * p;
    const uint himask = (p == 0) ? 0u : (0xFFFFFFFFu << (8 * (4 - p)));
    __syncthreads();
    for (int i = t; i < 16 * 129; i += 256) hist[i] = 0;
    __syncthreads();
    uint* hr = hist + (r * 2 + (j & 1)) * 129;
    for (int i = j; i < LTOT; i += 32) {        // stride-1 per team: conflict-free
      const uint u = fkey(S2[r * LTOT + i]);
      if ((u & himask) == prefix) {
        const uint bin = (u >> shift) & 255u;
        atomicAdd(&hr[bin >> 1], (bin & 1) ? 65536u : 1u);
      }
    }
    __syncthreads();
    // lane j covers bins [8j, 8j+7]
    uint c = 0;
#pragma unroll
    for (int bb = 0; bb < 8; ++bb) {
      const int bin = j * 8 + bb;
      const uint w = hist[(r*2+0)*129 + (bin>>1)] + hist[(r*2+1)*129 + (bin>>1)];
      c += (bin & 1) ? (w >> 16) : (w & 0xFFFFu);
    }
    uint sfx = c;  // suffix sum over lanes >= j (descending-bin cumulative)
#pragma unroll
    for (int off = 1; off < 32; off <<= 1) {
      const uint o = __shfl_down(sfx, off, 32);
      if (j + off < 32) sfx += o;
    }
    const unsigned long long bal = __ballot(sfx >= rem);
    const uint halfb = (uint)(bal >> (t & 32));
    const int gs = 31 - __clz((int)halfb);         // highest lane with sfx >= rem
    uint above = __shfl(sfx, (gs + 1) & 31, 32);
    if (gs == 31) above = 0;
    uint rem2 = rem - above;
    int selbin = gs * 8;
#pragma unroll
    for (int bb = 7; bb >= 0; --bb) {
      const int bin = gs * 8 + bb;
      const uint w = hist[(r*2+0)*129 + (bin>>1)] + hist[(r*2+1)*129 + (bin>>1)];
      const uint cnt = (bin & 1) ? (w >> 16) : (w & 0xFFFFu);
      if (rem2 <= cnt) { selbin = bin; break; }
      rem2 -= cnt;
    }
    prefix |= ((uint)selbin) << shift;
    rem = rem2;
  }
  const uint T = prefix;   // key of the NKEEP-th largest score in this row

  // ---------------- softmax over kept; pack P=(bf16hi|bf16lo) in place ------
  float mx = -3.0e38f;
  for (int i = j; i < LTOT; i += 32) mx = fmaxf(mx, S2[r * LTOT + i]);
#pragma unroll
  for (int off = 16; off; off >>= 1) mx = fmaxf(mx, __shfl_xor(mx, off, 32));
  float z = 0.f;
  {
    const int xr = (r & 3) << 3;        // bits 3-4 only: race-free, full bank spread
    uint* S2u = (uint*)S2;
    for (int i = j; i < LTOT; i += 32) {
      const float s = S2[r * LTOT + i];
      const float e = (fkey(s) >= T) ? __expf(s - mx) : 0.f;
      z += e;
      ushort ph, pl; bf16split(e, ph, pl);
      S2u[r * LTOT + (i ^ xr)] = (uint)ph | ((uint)pl << 16);
    }
  }
#pragma unroll
  for (int off = 16; off; off >>= 1) z += __shfl_xor(z, off, 32);
  float* rowZ = (float*)&U[2072];
  if (j == 0) rowZ[r] = z;
  __syncthreads();

  // ---------------- PV: MFMA, depth-2 V prefetch, split-m across waves ------
  {
    f32x4 acc0 = {0.f,0.f,0.f,0.f}, acc1 = {0.f,0.f,0.f,0.f};
    f32x4 acc2 = {0.f,0.f,0.f,0.f}, acc3 = {0.f,0.f,0.f,0.f};
    const int arow = (c15 < 8) ? c15 : 7;   // clamp junk rows
    const int xr = (arow & 3) << 3;          // matches pack swizzle
    const uint* S2u = (const uint*)S2;
    bf16x8 vn0,vn1,vn2,vn3,vn4,vn5,vn6,vn7;
#pragma unroll
    for (int ks = 0; ks < 11; ++ks) {
      if (ks < 10) {
        LDV(vn0,vn1, 0,ks+1); LDV(vn2,vn3, 1,ks+1);
        LDV(vn4,vn5, 2,ks+1); LDV(vn6,vn7, 3,ks+1);
      }
      const int mw = g * 352 + ks * 32 + 8 * h4;
      const int W0 = arow * LTOT + (mw ^ xr);
      const uint4 ua = *(const uint4*)&S2u[W0];
      const uint4 ub = *(const uint4*)&S2u[W0 + 4];
      uint4 ahv, alv;
      ahv.x = (ua.x & 0xFFFFu) | (ua.y << 16);
      alv.x = (ua.x >> 16) | (ua.y & 0xFFFF0000u);
      ahv.y = (ua.z & 0xFFFFu) | (ua.w << 16);
      alv.y = (ua.z >> 16) | (ua.w & 0xFFFF0000u);
      ahv.z = (ub.x & 0xFFFFu) | (ub.y << 16);
      alv.z = (ub.x >> 16) | (ub.y & 0xFFFF0000u);
      ahv.w = (ub.z & 0xFFFFu) | (ub.w << 16);
      alv.w = (ub.z >> 16) | (ub.w & 0xFFFF0000u);
      const bf16x8 aH = *(const bf16x8*)&ahv;
      const bf16x8 aL = *(const bf16x8*)&alv;
      __builtin_amdgcn_s_setprio(1);
      acc0 = __builtin_amdgcn_mfma_f32_16x16x32_bf16(aH, vc0, acc0, 0, 0, 0);
      acc1 = __builtin_amdgcn_mfma_f32_16x16x32_bf16(aH, vc2, acc1, 0, 0, 0);
      acc2 = __builtin_amdgcn_mfma_f32_16x16x32_bf16(aH, vc4, acc2, 0, 0, 0);
      acc3 = __builtin_amdgcn_mfma_f32_16x16x32_bf16(aH, vc6, acc3, 0, 0, 0);
      acc0 = __builtin_amdgcn_mfma_f32_16x16x32_bf16(aH, vc1, acc0, 0, 0, 0);
      acc1 = __builtin_amdgcn_mfma_f32_16x16x32_bf16(aH, vc3, acc1, 0, 0, 0);
      acc2 = __builtin_amdgcn_mfma_f32_16x16x32_bf16(aH, vc5, acc2, 0, 0, 0);
      acc3 = __builtin_amdgcn_mfma_f32_16x16x32_bf16(aH, vc7, acc3, 0, 0, 0);
      acc0 = __builtin_amdgcn_mfma_f32_16x16x32_bf16(aL, vc0, acc0, 0, 0, 0);
      acc1 = __builtin_amdgcn_mfma_f32_16x16x32_bf16(aL, vc2, acc1, 0, 0, 0);
      acc2 = __builtin_amdgcn_mfma_f32_16x16x32_bf16(aL, vc4, acc2, 0, 0, 0);
      acc3 = __builtin_amdgcn_mfma_f32_16x16x32_bf16(aL, vc6, acc3, 0, 0, 0);
      __builtin_amdgcn_s_setprio(0);
      vc0 = vn0; vc1 = vn1; vc2 = vn2; vc3 = vn3;
      vc4 = vn4; vc5 = vn5; vc6 = vn6; vc7 = vn7;
    }
#undef LDV
    float* red = (float*)U;   // [4][8][64]
    if (lane < 32) {
#pragma unroll
      for (int q = 0; q < 4; ++q) {
        const int rr = 4 * h4 + q;     // h4 in {0,1}: rows 0-7 valid
        red[g * 512 + rr * 64 +  0 + c15] = acc0[q];
        red[g * 512 + rr * 64 + 16 + c15] = acc1[q];
        red[g * 512 + rr * 64 + 32 + c15] = acc2[q];
        red[g * 512 + rr * 64 + 48 + c15] = acc3[q];
      }
    }
  }
  __syncthreads();
  {
    float* red = (float*)U;
    float* rowZp = (float*)&U[2072];
    for (int idx = t; idx < 512; idx += 256) {
      const int rr = idx >> 6, ln = idx & 63;
      const float o = (red[rr*64+ln] + red[512 + rr*64+ln] +
                       red[1024 + rr*64+ln] + red[1536 + rr*64+ln]) / rowZp[rr];
      AO[((size_t)b * LTOT + (l0 + rr)) * DIMD + h * HD + ln] = o;
    }
  }
}

// ---------------------------------------------------------------------------
extern "C" void kernel_launch(void* const* d_in, const int* in_sizes, int n_in,
                              void* d_out, int out_size, void* d_ws, size_t ws_size,
                              hipStream_t stream)
{
  (void)in_sizes; (void)n_in; (void)out_size; (void)ws_size;
  const float* x  = (const float*)d_in[0];
  const float* qw = (const float*)d_in[1];
  const float* pw = (const float*)d_in[2];
  const float* pb = (const float*)d_in[3];
  const float* rw = (const float*)d_in[4];
  const float* rm = (const float*)d_in[5];
  float* out = (float*)d_out;
  float* ws  = (float*)d_ws;

  const size_t NQ = (size_t)BATCH * HEADS * LTOT * HD;     // 2,883,584 elems
  ushort* QH = (ushort*)ws;            // 6 ushort planes = 3*NQ floats
  ushort* QL = QH + NQ;
  ushort* KH = QH + 2 * NQ;
  ushort* KL = QH + 3 * NQ;
  ushort* VH = QH + 4 * NQ;            // transposed [B,H,64,L]
  ushort* VL = QH + 5 * NQ;
  float*  AO = ws + 3 * NQ;                                 // [B, L, 512]
  float*  sCo = ws + 4 * NQ;                                // 1408*32 floats
  int*    sId = (int*)(ws + 4 * NQ + LTOT * SCAP);          // 1408*32 ints
  int*    sCn = (int*)(ws + 4 * NQ + 2 * LTOT * SCAP);      // 1408 ints
  // total ws: 4*NQ + 2*45,056 + 1,408 floats = 46.5 MB

  sbias_k<<<dim3(352), dim3(256), 0, stream>>>(rm, sId, sCo, sCn);
  gemm_k<0><<<dim3(44 * 12), dim3(256), 0, stream>>>(x, qw, nullptr, QH, QL, KH, KL, VH, VL, nullptr, 12);
  attn_k<<<dim3(32 * RBLK), dim3(256), 0, stream>>>(QH, QL, KH, KL, VH, VL, rw, sId, sCo, sCn, AO);
  gemm_k<1><<<dim3(44 * 4), dim3(256), 0, stream>>>(AO, pw, pb, nullptr, nullptr, nullptr, nullptr, nullptr, nullptr, out, 4);
}

// Round 10
// 802.230 us; speedup vs baseline: 1.2533x; 1.1219x over previous
//
#include <hip/hip_runtime.h>
#include <stdint.h>

// Problem constants (fixed by reference)
#define BATCH 4
#define LTOT  1408      // NVARS*NPATCH = 22*64 = 32 lanes * 44 chunk
#define HEADS 8
#define HD    64
#define DIMD  512
#define NKEEP 704      // L - int(0.5*L)
#define RBLK  176      // LTOT/8
#define SCAP  32       // sparse-correction capacity per row (max actual = 28)

typedef unsigned int uint;
typedef unsigned short ushort;
typedef __attribute__((ext_vector_type(8))) short bf16x8;
typedef __attribute__((ext_vector_type(4))) float f32x4;

__device__ __forceinline__ uint fkey_u(uint u) {
  // order-preserving map float-bits -> uint (ascending)
  return u ^ ((uint)((int)u >> 31) | 0x80000000u);
}
__device__ __forceinline__ float unfkey(uint k) {
  // inverse of fkey_u
  return __uint_as_float((k & 0x80000000u) ? (k ^ 0x80000000u) : ~k);
}

// Split f32 into bf16 hi + bf16 lo (x ~= hi + lo, rel err ~2^-17). RNE.
__device__ __forceinline__ void bf16split(float x, ushort& hi, ushort& lo) {
  uint u = __float_as_uint(x);
  uint h = (u + 0x7FFFu + ((u >> 16) & 1u)) & 0xFFFF0000u;
  hi = (ushort)(h >> 16);
  float r = x - __uint_as_float(h);
  uint v = __float_as_uint(r);
  lo = (ushort)((v + 0x7FFFu + ((v >> 16) & 1u)) >> 16);
}

// ---------------------------------------------------------------------------
// GEMM: C[M,N] = A[M,512] * W[N,512]^T.  128x128 tile, BK=16, 256 thr, 8x8 micro.
// MODE 0: qkv — Q,K as bf16 hi/lo planes [B,H,L,64] (q pre-scaled);
//               V as bf16 hi/lo planes TRANSPOSED [B,H,64,L] (for PV B-frags).
// MODE 1: proj — plain f32 store + bias add.
// ---------------------------------------------------------------------------
template<int MODE>
__global__ __launch_bounds__(256)
void gemm_k(const float* __restrict__ A, const float* __restrict__ W,
            const float* __restrict__ pb, ushort* __restrict__ QH,
            ushort* __restrict__ QL, ushort* __restrict__ KH,
            ushort* __restrict__ KL, ushort* __restrict__ VH,
            ushort* __restrict__ VL, float* __restrict__ C0, int ntiles)
{
  __shared__ float Ast[16][132];   // k-major, pad 132 (16B-aligned rows, bank-shifted)
  __shared__ float Bst[16][132];
  const int t  = threadIdx.x;
  const int mt = blockIdx.x / ntiles, nt = blockIdx.x % ntiles;
  const int m0 = mt * 128, n0 = nt * 128;
  const int lr = t >> 2;            // 0..63
  const int lk = (t & 3) << 2;      // 0,4,8,12
  const int tr = t >> 4, tc = t & 15;

  float acc[8][8];
#pragma unroll
  for (int i = 0; i < 8; ++i)
#pragma unroll
    for (int j = 0; j < 8; ++j) acc[i][j] = 0.f;

  for (int k0 = 0; k0 < DIMD; k0 += 16) {
#pragma unroll
    for (int hh = 0; hh < 2; ++hh) {
      const int row = lr + hh * 64;
      const float4 av = *(const float4*)(A + (size_t)(m0 + row) * DIMD + k0 + lk);
      Ast[lk + 0][row] = av.x; Ast[lk + 1][row] = av.y;
      Ast[lk + 2][row] = av.z; Ast[lk + 3][row] = av.w;
      const float4 wv = *(const float4*)(W + (size_t)(n0 + row) * DIMD + k0 + lk);
      Bst[lk + 0][row] = wv.x; Bst[lk + 1][row] = wv.y;
      Bst[lk + 2][row] = wv.z; Bst[lk + 3][row] = wv.w;
    }
    __syncthreads();
#pragma unroll
    for (int k = 0; k < 16; ++k) {
      const float4 a0 = *(const float4*)&Ast[k][tr * 8];
      const float4 a1 = *(const float4*)&Ast[k][tr * 8 + 4];
      const float4 b0 = *(const float4*)&Bst[k][tc * 8];
      const float4 b1 = *(const float4*)&Bst[k][tc * 8 + 4];
      const float a[8] = {a0.x,a0.y,a0.z,a0.w,a1.x,a1.y,a1.z,a1.w};
      const float b[8] = {b0.x,b0.y,b0.z,b0.w,b1.x,b1.y,b1.z,b1.w};
#pragma unroll
      for (int i = 0; i < 8; ++i)
#pragma unroll
        for (int j = 0; j < 8; ++j)
          acc[i][j] = fmaf(a[i], b[j], acc[i][j]);
    }
    __syncthreads();
  }

  const int nb = n0 + tc * 8;
  if (MODE == 0) {
    // n in [0,1536): which = n>>9 (uniform per block), h = (n>>6)&7, d = n&63
    const int which = nb >> 9;
    const int h  = (nb >> 6) & 7;
    const int d0 = nb & 63;
    const float scl = (which == 0) ? 0.125f : 1.0f;   // fold q * HD^-0.5
    if (which == 2) {
      // V transposed: Vt[b,h,d,m], 8 consecutive m per store.
      const int bb = (m0 + tr * 8) / LTOT, ll0 = (m0 + tr * 8) % LTOT;
#pragma unroll
      for (int jp = 0; jp < 8; ++jp) {
        uint hw[4], lw[4];
#pragma unroll
        for (int ip = 0; ip < 4; ++ip) {
          ushort h0, l0v, h1, l1v;
          bf16split(acc[2*ip][jp],     h0, l0v);
          bf16split(acc[2*ip + 1][jp], h1, l1v);
          hw[ip] = (uint)h0 | ((uint)h1 << 16);
          lw[ip] = (uint)l0v | ((uint)l1v << 16);
        }
        const size_t off = ((size_t)(bb * HEADS + h) * 64 + (d0 + jp)) * LTOT + ll0;
        *(uint4*)(VH + off) = make_uint4(hw[0], hw[1], hw[2], hw[3]);
        *(uint4*)(VL + off) = make_uint4(lw[0], lw[1], lw[2], lw[3]);
      }
    } else {
      ushort* Hd = (which == 0) ? QH : KH;
      ushort* Ld = (which == 0) ? QL : KL;
#pragma unroll
      for (int i = 0; i < 8; ++i) {
        const int gm = m0 + tr * 8 + i;
        const int bb = gm / LTOT, ll = gm % LTOT;
        const size_t off = ((size_t)(bb * HEADS + h) * LTOT + ll) * HD + d0;
        uint hw[4], lw[4];
#pragma unroll
        for (int jp = 0; jp < 4; ++jp) {
          ushort h0, l0v, h1, l1v;
          bf16split(acc[i][2*jp]     * scl, h0, l0v);
          bf16split(acc[i][2*jp + 1] * scl, h1, l1v);
          hw[jp] = (uint)h0 | ((uint)h1 << 16);
          lw[jp] = (uint)l0v | ((uint)l1v << 16);
        }
        *(uint4*)(Hd + off) = make_uint4(hw[0], hw[1], hw[2], hw[3]);
        *(uint4*)(Ld + off) = make_uint4(lw[0], lw[1], lw[2], lw[3]);
      }
    }
  } else {
    const float4 q0 = *(const float4*)(pb + nb);
    const float4 q1 = *(const float4*)(pb + nb + 4);
#pragma unroll
    for (int i = 0; i < 8; ++i) {
      const int gm = m0 + tr * 8 + i;
      float* p = C0 + (size_t)gm * DIMD + nb;
      float4 v0 = make_float4(acc[i][0]+q0.x, acc[i][1]+q0.y, acc[i][2]+q0.z, acc[i][3]+q0.w);
      float4 v1 = make_float4(acc[i][4]+q1.x, acc[i][5]+q1.y, acc[i][6]+q1.z, acc[i][7]+q1.w);
      *(float4*)p = v0;
      *(float4*)(p + 4) = v1;
    }
  }
}

// ---------------------------------------------------------------------------
// Sparse-bias builder. bias[h,l,m] = w2[h] (row-const, ordering/softmax
// invariant -> skipped) + (w0-w2)*S[l,m] + (w1-w2)*T[l,m] - w2*eye[l,m].
// <=28 sparse entries/row. One wave per row l, ballot compaction.
// ---------------------------------------------------------------------------
__global__ __launch_bounds__(256)
void sbias_k(const float* __restrict__ masks, int* __restrict__ sIdx,
             float* __restrict__ sCoef, int* __restrict__ sCnt)
{
  const int l    = blockIdx.x * 4 + (threadIdx.x >> 6);   // 352 blocks * 4 waves
  const int lane = threadIdx.x & 63;
  const unsigned long long ltmask = (1ull << lane) - 1ull;
  const float* Sm = masks + ((size_t)l * 3 + 0) * LTOT;
  const float* Tm = masks + ((size_t)l * 3 + 1) * LTOT;
  int base = 0;
  for (int i = lane; i < LTOT; i += 64) {
    const float sv = Sm[i];
    const float tv = Tm[i];
    const unsigned long long bS = __ballot(sv != 0.f);
    if (sv != 0.f) {
      const int pos = base + __popcll(bS & ltmask);
      if (pos < SCAP) { sIdx[l * SCAP + pos] = (i << 2) | 0; sCoef[l * SCAP + pos] = sv; }
    }
    base += __popcll(bS);
    const unsigned long long bT = __ballot(tv != 0.f);
    if (tv != 0.f) {
      const int pos = base + __popcll(bT & ltmask);
      if (pos < SCAP) { sIdx[l * SCAP + pos] = (i << 2) | 1; sCoef[l * SCAP + pos] = tv; }
    }
    base += __popcll(bT);
    const unsigned long long bD = __ballot(i == l);
    if (i == l) {
      const int pos = base + __popcll(bD & ltmask);
      if (pos < SCAP) { sIdx[l * SCAP + pos] = (i << 2) | 2; sCoef[l * SCAP + pos] = 1.f; }
    }
    base += __popcll(bD);
  }
  if (lane == 0) sCnt[l] = (base < SCAP) ? base : SCAP;
}

// ---------------------------------------------------------------------------
// Fused attention: per block = 8 query rows of one (b,h).
// Scores: bf16 MFMA, 3-term hi/lo, depth-2 pipeline with sched_barrier(0)
//   pinning loads before the MFMA cluster (r9: compiler sank them, VGPR=68).
// Radix/softmax: REGISTER-CACHED KEYS — each lane caches its 44-elem chunk's
//   fkeys (11 x ds_read_b128, one pipelined burst), then 4 radix passes, the
//   umax row-max, and the exp pass all run from VGPRs (zero LDS scan reads).
//   fkey is a bijection; exp uses unfkey. P packed (bf16hi|lo) to S2u with
//   ^xr (bits 3-4) col swizzle — all-distinct addresses, race-free.
// PV: MFMA, depth-2 V prefetch (pinned), split-m; reduce in red, /Z, store.
// LDS: S2 44KB + U 8.3KB = 53.4KB => 3 blk/CU. XCD-chunked block swizzle.
// ---------------------------------------------------------------------------
__global__ __launch_bounds__(256, 3)
void attn_k(const ushort* __restrict__ QH, const ushort* __restrict__ QL,
            const ushort* __restrict__ KH, const ushort* __restrict__ KL,
            const ushort* __restrict__ VH, const ushort* __restrict__ VL,
            const float* __restrict__ rw,
            const int* __restrict__ sIdx, const float* __restrict__ sCoef,
            const int* __restrict__ sCnt, float* __restrict__ AO)
{
  __shared__ float S2[8 * LTOT];       // 45056B row-major: S2[r*1408 + m]
  __shared__ uint  U[2080];            // 8320B: hist 16*129 | red 2048 f32; rowZ @2072

  const int t   = threadIdx.x;
  // XCD-chunked bijective swizzle: 5632 = 8 * 704 exactly.
  const int bid = (int)((blockIdx.x & 7) * 704 + (blockIdx.x >> 3));
  const int bh = bid / RBLK;
  const int rb = bid % RBLK;
  const int l0 = rb * 8;
  const int b  = bh >> 3, h = bh & 7;

  const int lane = t & 63;
  const int g    = t >> 6;             // wave id
  const int c15  = lane & 15;
  const int h4   = lane >> 4;

  // ---------------- scores (MFMA, depth-2 pipeline, pinned) ----------------
  {
    int ar = l0 + c15;
    if (ar >= LTOT) ar = LTOT - 1;
    const size_t qb = ((size_t)bh * LTOT + ar) * HD + 8 * h4;
    const bf16x8 aH0 = *(const bf16x8*)(QH + qb);
    const bf16x8 aH1 = *(const bf16x8*)(QH + qb + 32);
    const bf16x8 aL0 = *(const bf16x8*)(QL + qb);
    const bf16x8 aL1 = *(const bf16x8*)(QL + qb + 32);

    const size_t kb0 = (size_t)bh * LTOT * HD + 8 * h4;
    const int mb = g * 352 + c15;

    bf16x8 cA0,cA1,cA2,cA3, cB0,cB1,cB2,cB3;
    bf16x8 nA0,nA1,nA2,nA3, nB0,nB1,nB2,nB3;
#define LDK4(d0,d1,d2,d3, mcol) do { const size_t kk = kb0 + (size_t)(mcol) * HD; \
    d0 = *(const bf16x8*)(KH + kk); d1 = *(const bf16x8*)(KH + kk + 32); \
    d2 = *(const bf16x8*)(KL + kk); d3 = *(const bf16x8*)(KL + kk + 32); } while(0)
    LDK4(cA0,cA1,cA2,cA3, mb);
    LDK4(cB0,cB1,cB2,cB3, mb + 16);
#pragma unroll
    for (int it = 0; it < 11; ++it) {
      if (it < 10) {
        LDK4(nA0,nA1,nA2,nA3, mb + (it + 1) * 32);
        LDK4(nB0,nB1,nB2,nB3, mb + (it + 1) * 32 + 16);
      }
      __builtin_amdgcn_sched_barrier(0);   // pin: prefetch loads stay ABOVE MFMAs
      f32x4 s0 = {0.f,0.f,0.f,0.f}, s1 = {0.f,0.f,0.f,0.f};
      __builtin_amdgcn_s_setprio(1);
      s0 = __builtin_amdgcn_mfma_f32_16x16x32_bf16(aH0, cA0, s0, 0, 0, 0);
      s1 = __builtin_amdgcn_mfma_f32_16x16x32_bf16(aH0, cB0, s1, 0, 0, 0);
      s0 = __builtin_amdgcn_mfma_f32_16x16x32_bf16(aH1, cA1, s0, 0, 0, 0);
      s1 = __builtin_amdgcn_mfma_f32_16x16x32_bf16(aH1, cB1, s1, 0, 0, 0);
      s0 = __builtin_amdgcn_mfma_f32_16x16x32_bf16(aH0, cA2, s0, 0, 0, 0);
      s1 = __builtin_amdgcn_mfma_f32_16x16x32_bf16(aH0, cB2, s1, 0, 0, 0);
      s0 = __builtin_amdgcn_mfma_f32_16x16x32_bf16(aH1, cA3, s0, 0, 0, 0);
      s1 = __builtin_amdgcn_mfma_f32_16x16x32_bf16(aH1, cB3, s1, 0, 0, 0);
      s0 = __builtin_amdgcn_mfma_f32_16x16x32_bf16(aL0, cA0, s0, 0, 0, 0);
      s1 = __builtin_amdgcn_mfma_f32_16x16x32_bf16(aL0, cB0, s1, 0, 0, 0);
      s0 = __builtin_amdgcn_mfma_f32_16x16x32_bf16(aL1, cA1, s0, 0, 0, 0);
      s1 = __builtin_amdgcn_mfma_f32_16x16x32_bf16(aL1, cB1, s1, 0, 0, 0);
      __builtin_amdgcn_s_setprio(0);
      if (lane < 32) {
        const int r0 = 4 * h4;            // h4 in {0,1} here
        const int mA = g * 352 + it * 32 + c15;
        S2[(r0 + 0) * LTOT + mA] = s0[0];
        S2[(r0 + 1) * LTOT + mA] = s0[1];
        S2[(r0 + 2) * LTOT + mA] = s0[2];
        S2[(r0 + 3) * LTOT + mA] = s0[3];
        S2[(r0 + 0) * LTOT + mA + 16] = s1[0];
        S2[(r0 + 1) * LTOT + mA + 16] = s1[1];
        S2[(r0 + 2) * LTOT + mA + 16] = s1[2];
        S2[(r0 + 3) * LTOT + mA + 16] = s1[3];
      }
      cA0 = nA0; cA1 = nA1; cA2 = nA2; cA3 = nA3;
      cB0 = nB0; cB1 = nB1; cB2 = nB2; cB3 = nB3;
    }
#undef LDK4
  }
  __syncthreads();

  // ---- pre-issue PV ks=0 V-frags NOW: latency hides under radix+softmax ----
  const size_t vb0 = (size_t)bh * 64 * LTOT + (size_t)c15 * LTOT + g * 352 + 8 * h4;
#define LDV(dH, dL, ntv, ksv) do { const size_t vv = vb0 + (size_t)(ntv) * 16 * LTOT + (ksv) * 32; \
    dH = *(const bf16x8*)(VH + vv); dL = *(const bf16x8*)(VL + vv); } while(0)
  bf16x8 vc0,vc1,vc2,vc3,vc4,vc5,vc6,vc7;
  LDV(vc0,vc1, 0,0); LDV(vc2,vc3, 1,0); LDV(vc4,vc5, 2,0); LDV(vc6,vc7, 3,0);

  // ---------------- sparse bias corrections (<=28 per row) ----------------
  {
    const int rr = t >> 5, jj = t & 31;
    const int l  = l0 + rr;
    if (jj < sCnt[l]) {
      const int   e = sIdx[l * SCAP + jj];
      const float c = sCoef[l * SCAP + jj];
      const int   m = e >> 2, ty = e & 3;
      const float w0 = rw[h * 3 + 0], w1 = rw[h * 3 + 1], w2 = rw[h * 3 + 2];
      const float d = (ty == 0) ? (w0 - w2) * c
                    : (ty == 1) ? (w1 - w2) * c
                                : -w2 * c;
      S2[rr * LTOT + m] += d;     // unique (m,rr) per entry -> no atomics
    }
  }
  __syncthreads();

  // -------- load row-chunk keys into registers (11 x b128, pipelined) -------
  const int r = t >> 5, j = t & 31;     // 32 lanes per row; chunk = [44j, 44j+44)
  const uint* S2uc = (const uint*)S2;
  uint key[44];
  uint maxk = 0;
#pragma unroll
  for (int c = 0; c < 11; ++c) {
    const uint4 v = *(const uint4*)&S2uc[r * LTOT + j * 44 + 4 * c];
    key[4*c+0] = fkey_u(v.x); key[4*c+1] = fkey_u(v.y);
    key[4*c+2] = fkey_u(v.z); key[4*c+3] = fkey_u(v.w);
    maxk = max(maxk, max(max(key[4*c+0], key[4*c+1]), max(key[4*c+2], key[4*c+3])));
  }

  // ---------------- exact top-NKEEP threshold (radix from registers) --------
  uint* hist = U;                        // 16 sub-hists (2/row) of 129 u16-pair words
  uint prefix = 0, rem = NKEEP;
#pragma unroll
  for (int p = 0; p < 4; ++p) {
    const int shift = 24 - 8 * p;
    const uint himask = (p == 0) ? 0u : (0xFFFFFFFFu << (8 * (4 - p)));
    __syncthreads();
    for (int i = t; i < 16 * 129; i += 256) hist[i] = 0;
    __syncthreads();
    uint* hr = hist + (r * 2 + (j & 1)) * 129;
#pragma unroll
    for (int c = 0; c < 44; ++c) {
      const uint u = key[c];
      if ((u & himask) == prefix) {
        const uint bin = (u >> shift) & 255u;
        atomicAdd(&hr[bin >> 1], (bin & 1) ? 65536u : 1u);
      }
    }
    __syncthreads();
    // lane j covers bins [8j, 8j+7]
    uint c = 0;
#pragma unroll
    for (int bb = 0; bb < 8; ++bb) {
      const int bin = j * 8 + bb;
      const uint w = hist[(r*2+0)*129 + (bin>>1)] + hist[(r*2+1)*129 + (bin>>1)];
      c += (bin & 1) ? (w >> 16) : (w & 0xFFFFu);
    }
    uint sfx = c;  // suffix sum over lanes >= j (descending-bin cumulative)
#pragma unroll
    for (int off = 1; off < 32; off <<= 1) {
      const uint o = __shfl_down(sfx, off, 32);
      if (j + off < 32) sfx += o;
    }
    const unsigned long long bal = __ballot(sfx >= rem);
    const uint halfb = (uint)(bal >> (t & 32));
    const int gs = 31 - __clz((int)halfb);         // highest lane with sfx >= rem
    uint above = __shfl(sfx, (gs + 1) & 31, 32);
    if (gs == 31) above = 0;
    uint rem2 = rem - above;
    int selbin = gs * 8;
#pragma unroll
    for (int bb = 7; bb >= 0; --bb) {
      const int bin = gs * 8 + bb;
      const uint w = hist[(r*2+0)*129 + (bin>>1)] + hist[(r*2+1)*129 + (bin>>1)];
      const uint cnt = (bin & 1) ? (w >> 16) : (w & 0xFFFFu);
      if (rem2 <= cnt) { selbin = bin; break; }
      rem2 -= cnt;
    }
    prefix |= ((uint)selbin) << shift;
    rem = rem2;
  }
  const uint T = prefix;   // key of the NKEEP-th largest score in this row

  // ---------------- softmax from registers; pack P=(bf16hi|lo) to LDS ------
#pragma unroll
  for (int off = 16; off; off >>= 1) maxk = max(maxk, (uint)__shfl_xor((int)maxk, off, 32));
  const float mx = unfkey(maxk);
  float z = 0.f;
  {
    const int xr = (r & 3) << 3;        // bits 3-4 swizzle, matches PV read
    uint* S2u = (uint*)S2;
#pragma unroll
    for (int c = 0; c < 11; ++c) {
      uint out[4];
#pragma unroll
      for (int q = 0; q < 4; ++q) {
        const uint u = key[4*c+q];
        const float e = (u >= T) ? __expf(unfkey(u) - mx) : 0.f;
        z += e;
        ushort ph, pl; bf16split(e, ph, pl);
        out[q] = (uint)ph | ((uint)pl << 16);
      }
      // (base^xr)+q == (base+q)^xr for base%4==0, q<4 (xr has bits 3-4 only)
      *(uint4*)&S2u[r * LTOT + ((j * 44 + 4 * c) ^ xr)] =
          make_uint4(out[0], out[1], out[2], out[3]);
    }
  }
#pragma unroll
  for (int off = 16; off; off >>= 1) z += __shfl_xor(z, off, 32);
  float* rowZ = (float*)&U[2072];
  if (j == 0) rowZ[r] = z;
  __syncthreads();

  // ---------------- PV: MFMA, depth-2 V prefetch (pinned), split-m ----------
  {
    f32x4 acc0 = {0.f,0.f,0.f,0.f}, acc1 = {0.f,0.f,0.f,0.f};
    f32x4 acc2 = {0.f,0.f,0.f,0.f}, acc3 = {0.f,0.f,0.f,0.f};
    const int arow = (c15 < 8) ? c15 : 7;   // clamp junk rows
    const int xr = (arow & 3) << 3;          // matches pack swizzle
    const uint* S2u = (const uint*)S2;
    bf16x8 vn0,vn1,vn2,vn3,vn4,vn5,vn6,vn7;
#pragma unroll
    for (int ks = 0; ks < 11; ++ks) {
      if (ks < 10) {
        LDV(vn0,vn1, 0,ks+1); LDV(vn2,vn3, 1,ks+1);
        LDV(vn4,vn5, 2,ks+1); LDV(vn6,vn7, 3,ks+1);
      }
      const int mw = g * 352 + ks * 32 + 8 * h4;
      const int W0 = arow * LTOT + (mw ^ xr);
      const uint4 ua = *(const uint4*)&S2u[W0];
      const uint4 ub = *(const uint4*)&S2u[W0 + 4];
      __builtin_amdgcn_sched_barrier(0);   // pin: V prefetch + P reads above MFMAs
      uint4 ahv, alv;
      ahv.x = (ua.x & 0xFFFFu) | (ua.y << 16);
      alv.x = (ua.x >> 16) | (ua.y & 0xFFFF0000u);
      ahv.y = (ua.z & 0xFFFFu) | (ua.w << 16);
      alv.y = (ua.z >> 16) | (ua.w & 0xFFFF0000u);
      ahv.z = (ub.x & 0xFFFFu) | (ub.y << 16);
      alv.z = (ub.x >> 16) | (ub.y & 0xFFFF0000u);
      ahv.w = (ub.z & 0xFFFFu) | (ub.w << 16);
      alv.w = (ub.z >> 16) | (ub.w & 0xFFFF0000u);
      const bf16x8 aH = *(const bf16x8*)&ahv;
      const bf16x8 aL = *(const bf16x8*)&alv;
      __builtin_amdgcn_s_setprio(1);
      acc0 = __builtin_amdgcn_mfma_f32_16x16x32_bf16(aH, vc0, acc0, 0, 0, 0);
      acc1 = __builtin_amdgcn_mfma_f32_16x16x32_bf16(aH, vc2, acc1, 0, 0, 0);
      acc2 = __builtin_amdgcn_mfma_f32_16x16x32_bf16(aH, vc4, acc2, 0, 0, 0);
      acc3 = __builtin_amdgcn_mfma_f32_16x16x32_bf16(aH, vc6, acc3, 0, 0, 0);
      acc0 = __builtin_amdgcn_mfma_f32_16x16x32_bf16(aH, vc1, acc0, 0, 0, 0);
      acc1 = __builtin_amdgcn_mfma_f32_16x16x32_bf16(aH, vc3, acc1, 0, 0, 0);
      acc2 = __builtin_amdgcn_mfma_f32_16x16x32_bf16(aH, vc5, acc2, 0, 0, 0);
      acc3 = __builtin_amdgcn_mfma_f32_16x16x32_bf16(aH, vc7, acc3, 0, 0, 0);
      acc0 = __builtin_amdgcn_mfma_f32_16x16x32_bf16(aL, vc0, acc0, 0, 0, 0);
      acc1 = __builtin_amdgcn_mfma_f32_16x16x32_bf16(aL, vc2, acc1, 0, 0, 0);
      acc2 = __builtin_amdgcn_mfma_f32_16x16x32_bf16(aL, vc4, acc2, 0, 0, 0);
      acc3 = __builtin_amdgcn_mfma_f32_16x16x32_bf16(aL, vc6, acc3, 0, 0, 0);
      __builtin_amdgcn_s_setprio(0);
      vc0 = vn0; vc1 = vn1; vc2 = vn2; vc3 = vn3;
      vc4 = vn4; vc5 = vn5; vc6 = vn6; vc7 = vn7;
    }
#undef LDV
    float* red = (float*)U;   // [4][8][64]
    if (lane < 32) {
#pragma unroll
      for (int q = 0; q < 4; ++q) {
        const int rr = 4 * h4 + q;     // h4 in {0,1}: rows 0-7 valid
        red[g * 512 + rr * 64 +  0 + c15] = acc0[q];
        red[g * 512 + rr * 64 + 16 + c15] = acc1[q];
        red[g * 512 + rr * 64 + 32 + c15] = acc2[q];
        red[g * 512 + rr * 64 + 48 + c15] = acc3[q];
      }
    }
  }
  __syncthreads();
  {
    float* red = (float*)U;
    float* rowZp = (float*)&U[2072];
    for (int idx = t; idx < 512; idx += 256) {
      const int rr = idx >> 6, ln = idx & 63;
      const float o = (red[rr*64+ln] + red[512 + rr*64+ln] +
                       red[1024 + rr*64+ln] + red[1536 + rr*64+ln]) / rowZp[rr];
      AO[((size_t)b * LTOT + (l0 + rr)) * DIMD + h * HD + ln] = o;
    }
  }
}

// ---------------------------------------------------------------------------
extern "C" void kernel_launch(void* const* d_in, const int* in_sizes, int n_in,
                              void* d_out, int out_size, void* d_ws, size_t ws_size,
                              hipStream_t stream)
{
  (void)in_sizes; (void)n_in; (void)out_size; (void)ws_size;
  const float* x  = (const float*)d_in[0];
  const float* qw = (const float*)d_in[1];
  const float* pw = (const float*)d_in[2];
  const float* pb = (const float*)d_in[3];
  const float* rw = (const float*)d_in[4];
  const float* rm = (const float*)d_in[5];
  float* out = (float*)d_out;
  float* ws  = (float*)d_ws;

  const size_t NQ = (size_t)BATCH * HEADS * LTOT * HD;     // 2,883,584 elems
  ushort* QH = (ushort*)ws;            // 6 ushort planes = 3*NQ floats
  ushort* QL = QH + NQ;
  ushort* KH = QH + 2 * NQ;
  ushort* KL = QH + 3 * NQ;
  ushort* VH = QH + 4 * NQ;            // transposed [B,H,64,L]
  ushort* VL = QH + 5 * NQ;
  float*  AO = ws + 3 * NQ;                                 // [B, L, 512]
  float*  sCo = ws + 4 * NQ;                                // 1408*32 floats
  int*    sId = (int*)(ws + 4 * NQ + LTOT * SCAP);          // 1408*32 ints
  int*    sCn = (int*)(ws + 4 * NQ + 2 * LTOT * SCAP);      // 1408 ints
  // total ws: 4*NQ + 2*45,056 + 1,408 floats = 46.5 MB

  sbias_k<<<dim3(352), dim3(256), 0, stream>>>(rm, sId, sCo, sCn);
  gemm_k<0><<<dim3(44 * 12), dim3(256), 0, stream>>>(x, qw, nullptr, QH, QL, KH, KL, VH, VL, nullptr, 12);
  attn_k<<<dim3(32 * RBLK), dim3(256), 0, stream>>>(QH, QL, KH, KL, VH, VL, rw, sId, sCo, sCn, AO);
  gemm_k<1><<<dim3(44 * 4), dim3(256), 0, stream>>>(AO, pw, pb, nullptr, nullptr, nullptr, nullptr, nullptr, nullptr, out, 4);
}